// Round 1
// baseline (536.080 us; speedup 1.0000x reference)
//
#include <hip/hip_runtime.h>

// Problem: B=32, C=8, L=2048, K=512, S=64, W=1985
// out[b,0,k] = max(0, max_w  sum_c dot(xw_norm[b,c,w,:], sn_norm[c,k,:]) / C)

#define B_ 32
#define C_ 8
#define L_ 2048
#define K_ 512
#define S_ 64
#define W_ (L_ - S_ + 1)          // 1985
#define TW 64                     // windows per block tile
#define NTILES ((W_ + TW - 1) / TW)  // 32
#define XPAD 132                  // LDS row stride for x tile (127 used)

// ---------------- kernel 1: normalize shapelets -> snT[(c*64+s)*512 + k] ----
__global__ void norm_shapelets_k(const float* __restrict__ sh,
                                 float* __restrict__ snT) {
    int ck = blockIdx.x;             // 0..C_*K_-1
    int c = ck >> 9;                 // /512
    int k = ck & (K_ - 1);
    int s = threadIdx.x;             // 0..63
    float v = sh[(c * K_ + k) * S_ + s];
    float ss = v * v;
    #pragma unroll
    for (int off = 32; off > 0; off >>= 1) ss += __shfl_down(ss, off);
    ss = __shfl(ss, 0);
    float inv = 1.0f / fmaxf(sqrtf(ss), 1e-8f);
    snT[(c * S_ + s) * K_ + k] = v * inv;
}

// ---------------- kernel 2: main GEMM + relu + max ----------------
// grid: (NTILES, B_), block: 256 threads.
// thread (ty=tid>>4, tx=tid&15) computes 4 windows x 8 k per k-tile.
__global__ __launch_bounds__(256)
void mcs_main_k(const float* __restrict__ x,
                const float* __restrict__ snT,
                float* __restrict__ out) {
    __shared__ float xl[C_ * XPAD];      // x slice, stride-padded
    __shared__ float invn[C_ * TW];      // 0.125 / ||window||
    __shared__ float red[16 * 128];      // max-reduce scratch

    const int tile = blockIdx.x;
    const int b    = blockIdx.y;
    const int w0   = tile * TW;
    const int tid  = threadIdx.x;
    const int tx   = tid & 15;
    const int ty   = tid >> 4;
    const int ty4  = ty * 4;

    // stage x[b, c, w0 .. w0+126] (zero-fill OOB)
    for (int i = tid; i < C_ * 128; i += 256) {
        int c = i >> 7, j = i & 127;
        int idx = w0 + j;
        float v = 0.0f;
        if (j < 127 && idx < L_) v = x[(b * C_ + c) * L_ + idx];
        xl[c * XPAD + j] = v;
    }
    __syncthreads();

    // per-window inverse norms (fold in the 1/C = 0.125)
    for (int t = tid; t < C_ * TW; t += 256) {
        int c = t >> 6, wi = t & 63;
        const float* p = &xl[c * XPAD + wi];
        float ss = 0.0f;
        #pragma unroll
        for (int j = 0; j < S_; ++j) ss += p[j] * p[j];
        invn[t] = 0.125f / fmaxf(sqrtf(ss), 1e-8f);
    }
    __syncthreads();

    #pragma unroll 1
    for (int kt = 0; kt < K_ / 128; ++kt) {
        const int k0 = kt * 128;
        float acc[4][8];
        #pragma unroll
        for (int u = 0; u < 4; ++u)
            #pragma unroll
            for (int v = 0; v < 8; ++v) acc[u][v] = 0.0f;

        #pragma unroll 1
        for (int c = 0; c < C_; ++c) {
            float accc[4][8];
            #pragma unroll
            for (int u = 0; u < 4; ++u)
                #pragma unroll
                for (int v = 0; v < 8; ++v) accc[u][v] = 0.0f;

            const float* bp = snT + (c * S_) * K_ + k0 + tx * 8;
            const float* xp = &xl[c * XPAD + ty4];
            float a0 = xp[0], a1 = xp[1], a2 = xp[2];
            #pragma unroll 4
            for (int s = 0; s < S_; ++s) {
                float a3 = xp[3 + s];
                float4 b0 = *(const float4*)(bp);
                float4 b1 = *(const float4*)(bp + 4);
                float bb[8] = {b0.x, b0.y, b0.z, b0.w,
                               b1.x, b1.y, b1.z, b1.w};
                #pragma unroll
                for (int v = 0; v < 8; ++v) {
                    accc[0][v] += a0 * bb[v];
                    accc[1][v] += a1 * bb[v];
                    accc[2][v] += a2 * bb[v];
                    accc[3][v] += a3 * bb[v];
                }
                a0 = a1; a1 = a2; a2 = a3;
                bp += K_;
            }
            #pragma unroll
            for (int u = 0; u < 4; ++u) {
                float iv = invn[c * TW + ty4 + u];
                #pragma unroll
                for (int v = 0; v < 8; ++v) acc[u][v] += accc[u][v] * iv;
            }
        }

        // relu + max over this thread's 4 windows (mask invalid tail)
        float m[8];
        #pragma unroll
        for (int v = 0; v < 8; ++v) m[v] = 0.0f;
        #pragma unroll
        for (int u = 0; u < 4; ++u) {
            if (w0 + ty4 + u < W_) {
                #pragma unroll
                for (int v = 0; v < 8; ++v) m[v] = fmaxf(m[v], acc[u][v]);
            }
        }

        __syncthreads();   // red[] free from previous k-tile
        #pragma unroll
        for (int v = 0; v < 8; ++v) red[ty * 128 + tx * 8 + v] = m[v];
        __syncthreads();

        if (tid < 128) {
            float mv = 0.0f;
            #pragma unroll
            for (int t = 0; t < 16; ++t) mv = fmaxf(mv, red[t * 128 + tid]);
            // non-negative float: uint compare == float compare
            atomicMax((unsigned int*)&out[b * K_ + k0 + tid],
                      __float_as_uint(mv));
        }
    }
}

extern "C" void kernel_launch(void* const* d_in, const int* in_sizes, int n_in,
                              void* d_out, int out_size, void* d_ws, size_t ws_size,
                              hipStream_t stream) {
    const float* x  = (const float*)d_in[0];   // (32, 8, 2048) fp32
    const float* sh = (const float*)d_in[1];   // (8, 512, 64) fp32
    float* out = (float*)d_out;                // (32, 1, 512) fp32
    float* snT = (float*)d_ws;                 // 512*512 fp32 = 1 MB scratch

    // out is poisoned before every timed launch; relu floor is 0 -> memset 0
    hipMemsetAsync(out, 0, (size_t)out_size * sizeof(float), stream);

    norm_shapelets_k<<<dim3(C_ * K_), dim3(64), 0, stream>>>(sh, snT);
    mcs_main_k<<<dim3(NTILES, B_), dim3(256), 0, stream>>>(x, snT, out);
}

// Round 2
// 99.886 us; speedup vs baseline: 5.3669x; 5.3669x over previous
//
#include <hip/hip_runtime.h>

// B=32, C=8, L=2048, K=512, S=64, W=1985
// out[b,0,q] = max(0, max_w sum_c dot(xw_n[b,c,w,:], sn_n[c,q,:]) / 8)

#define B_ 32
#define C_ 8
#define L_ 2048
#define K_ 512
#define S_ 64
#define W_ (L_ - S_ + 1)              // 1985
#define TW 64                         // windows per block
#define NWT ((W_ + TW - 1) / TW)      // 32 window tiles
#define XP 128                        // xl row stride (floats)

typedef _Float16 f16x8 __attribute__((ext_vector_type(8)));
typedef float f32x4 __attribute__((ext_vector_type(4)));

// ---- kernel 1: normalize shapelets, pack fp16 in B-fragment order ----
// Bp[(((c*2+ks)*32 + nt)*64 + lane)*8 + j] =
//     sn_norm[c][nt*16 + (lane&15)][ks*32 + (lane>>4)*8 + j]
__global__ __launch_bounds__(64)
void pack_sn_k(const float* __restrict__ sh, _Float16* __restrict__ Bp) {
    const int blk  = blockIdx.x;          // 0..511 = c(8) x ks(2) x nt(32)
    const int c    = blk >> 6;
    const int ks   = (blk >> 5) & 1;
    const int nt   = blk & 31;
    const int lane = threadIdx.x;
    const int ncol = lane & 15, quad = lane >> 4;
    const int q    = nt * 16 + ncol;

    const float4* sp = (const float4*)(sh + (size_t)(c * K_ + q) * S_);
    float ss = 0.f;
    #pragma unroll
    for (int i = 0; i < 4; ++i) {
        float4 v = sp[quad * 4 + i];
        ss += v.x * v.x + v.y * v.y + v.z * v.z + v.w * v.w;
    }
    ss += __shfl_xor(ss, 16);
    ss += __shfl_xor(ss, 32);
    float inv = 1.f / fmaxf(sqrtf(ss), 1e-8f);

    float4 u0 = sp[ks * 8 + quad * 2];
    float4 u1 = sp[ks * 8 + quad * 2 + 1];
    f16x8 o;
    o[0] = (_Float16)(u0.x * inv); o[1] = (_Float16)(u0.y * inv);
    o[2] = (_Float16)(u0.z * inv); o[3] = (_Float16)(u0.w * inv);
    o[4] = (_Float16)(u1.x * inv); o[5] = (_Float16)(u1.y * inv);
    o[6] = (_Float16)(u1.z * inv); o[7] = (_Float16)(u1.w * inv);
    ((f16x8*)Bp)[((c * 2 + ks) * 32 + nt) * 64 + lane] = o;
}

// ---- kernel 2: MFMA GEMM + relu + max ----
// grid (NWT, B_), 256 threads = 4 waves.
// wave wid: 4 m-tiles (64 windows) x 8 n-tiles (128 shapelets at wid*128).
__global__ __launch_bounds__(256, 2)
void mcs_mfma_k(const float* __restrict__ x, const _Float16* __restrict__ Bp,
                float* __restrict__ out) {
    __shared__ float xl[C_ * XP];        // x slice fp32
    __shared__ float invn[C_ * TW];      // 0.125 / ||window||

    const int wt  = blockIdx.x;
    const int b   = blockIdx.y;
    const int w0  = wt * TW;
    const int tid = threadIdx.x;

    // stage x[b, c, w0 .. w0+126], zero-fill OOB
    for (int i = tid; i < C_ * XP; i += 256) {
        int c = i >> 7, p = i & 127;
        int pos = w0 + p;
        float v = 0.f;
        if (p < 127 && pos < L_) v = x[(size_t)(b * C_ + c) * L_ + pos];
        xl[i] = v;
    }
    __syncthreads();

    // per-window inverse norms (1/C folded in)
    for (int t = tid; t < C_ * TW; t += 256) {
        int c = t >> 6, m = t & 63;
        const float* p = xl + c * XP + m;
        float s0 = 0.f, s1 = 0.f, s2 = 0.f, s3 = 0.f;
        #pragma unroll
        for (int j = 0; j < S_; j += 4) {
            s0 += p[j] * p[j];     s1 += p[j + 1] * p[j + 1];
            s2 += p[j + 2] * p[j + 2]; s3 += p[j + 3] * p[j + 3];
        }
        float ss = (s0 + s1) + (s2 + s3);
        invn[t] = 0.125f / fmaxf(sqrtf(ss), 1e-8f);
    }
    __syncthreads();

    const int lane = tid & 63;
    const int wid  = tid >> 6;
    const int row  = lane & 15;
    const int quad = lane >> 4;
    const int ntb  = wid * 8;

    f32x4 acc[4][8];
    #pragma unroll
    for (int mt = 0; mt < 4; ++mt)
        #pragma unroll
        for (int nt = 0; nt < 8; ++nt)
            acc[mt][nt] = (f32x4){0.f, 0.f, 0.f, 0.f};

    #pragma unroll 1
    for (int c = 0; c < C_; ++c) {
        float iv[4];
        #pragma unroll
        for (int mt = 0; mt < 4; ++mt) iv[mt] = invn[c * TW + mt * 16 + row];

        #pragma unroll
        for (int ks = 0; ks < 2; ++ks) {
            // A fragments: A[m=row][k=quad*8+j] = xl[c][m + ks*32 + quad*8 + j] * invn
            f16x8 afr[4];
            #pragma unroll
            for (int mt = 0; mt < 4; ++mt) {
                const float* p = xl + c * XP + mt * 16 + row + ks * 32 + quad * 8;
                #pragma unroll
                for (int j = 0; j < 8; ++j)
                    afr[mt][j] = (_Float16)(p[j] * iv[mt]);
            }
            // B fragments: one dwordx4 each, packed layout
            const f16x8* bpp = (const f16x8*)Bp + ((c * 2 + ks) * 32 + ntb) * 64 + lane;
            f16x8 bfr[8];
            #pragma unroll
            for (int nt = 0; nt < 8; ++nt) bfr[nt] = bpp[nt * 64];

            #pragma unroll
            for (int nt = 0; nt < 8; ++nt)
                #pragma unroll
                for (int mt = 0; mt < 4; ++mt)
                    acc[mt][nt] = __builtin_amdgcn_mfma_f32_16x16x32_f16(
                        afr[mt], bfr[nt], acc[mt][nt], 0, 0, 0);
        }
    }

    // epilogue: relu + max over windows. C/D layout: col=lane&15, row=quad*4+r
    #pragma unroll
    for (int nt = 0; nt < 8; ++nt) {
        float m = 0.f;
        #pragma unroll
        for (int mt = 0; mt < 4; ++mt) {
            #pragma unroll
            for (int r = 0; r < 4; ++r) {
                int w = w0 + mt * 16 + quad * 4 + r;
                if (w < W_) m = fmaxf(m, acc[mt][nt][r]);
            }
        }
        m = fmaxf(m, __shfl_xor(m, 16));
        m = fmaxf(m, __shfl_xor(m, 32));
        if (lane < 16)
            atomicMax((unsigned int*)(out + b * K_ + (ntb + nt) * 16 + lane),
                      __float_as_uint(m));
    }
}

extern "C" void kernel_launch(void* const* d_in, const int* in_sizes, int n_in,
                              void* d_out, int out_size, void* d_ws, size_t ws_size,
                              hipStream_t stream) {
    const float* x  = (const float*)d_in[0];   // (32, 8, 2048) fp32
    const float* sh = (const float*)d_in[1];   // (8, 512, 64) fp32
    float* out = (float*)d_out;                // (32, 1, 512) fp32
    _Float16* Bp = (_Float16*)d_ws;            // 512 KB packed shapelets

    hipMemsetAsync(out, 0, (size_t)out_size * sizeof(float), stream);
    pack_sn_k<<<dim3(512), dim3(64), 0, stream>>>(sh, Bp);
    mcs_mfma_k<<<dim3(NWT, B_), dim3(256), 0, stream>>>(x, Bp, out);
}